// Round 9
// baseline (722.214 us; speedup 1.0000x reference)
//
#include <hip/hip_runtime.h>

// GRUModel: 2-layer GRU (H=64), B=4096, T=512, fp32 in/out — MFMA round 9.
//
// R9 = R8 (single-fp16 MFMA, layer-pipelined wave specialization, 614us)
// with the in-loop __syncthreads REMOVED: ring buffers (depth 4) + per-wave
// progress flags in LDS. Producer: release fence -> lane0 flag store (DS pipe
// in-order per wave => flag visible implies data visible). Consumer: spin on
// min(group flags) >= need, then acquire fence. Arithmetic is bit-identical
// to R8 -> absmax must reproduce 4.8828e-4 (built-in race detector).
//
// Dependence protocol (prog[w] = steps completed by wave w):
//   L0@t: needs peers' h0(t-1)            -> min(prog0) >= t
//         overwrites h0 slot t%4 (=h0(t-4)), last read by L1@t-4
//                                          -> min(prog1) >= t-3
//   L1@s: needs h0(s)                     -> min(prog0) >= s+1
//         needs peers' h1(s-1)            -> min(prog1) >= s
//         (h1 slot overwrite implied by min(prog1) >= s)
// Acyclic (L0 leads, L1 back-pressures via ring) -> deadlock-free.
//
// Frag layouts (m89/m120-verified):
//   A: lane holds A[m=lane&15][k=(lane>>4)*8+j], j=0..7
//   B: lane holds B[k=(lane>>4)*8+j][n=lane&15]
//   C/D: lane holds D[m=(lane>>4)*4+reg][n=lane&15]

typedef _Float16 half8 __attribute__((ext_vector_type(8)));
typedef float    v4f   __attribute__((ext_vector_type(4)));

#define T_LEN 512
#define KS 72   // fp16 row stride of h planes (16B-aligned b128 reads)
#define NSLOT 4

static __device__ __forceinline__ float sigm(float x) {
    return 1.0f / (1.0f + __expf(-x));
}
static __device__ __forceinline__ float tanh_fast(float x) {
    return 2.0f / (1.0f + __expf(-2.0f * x)) - 1.0f;
}
static __device__ __forceinline__ v4f mfma16(half8 a, half8 b, v4f c) {
    return __builtin_amdgcn_mfma_f32_16x16x32_f16(a, b, c, 0, 0, 0);
}
static __device__ __forceinline__ half8 ld8(const _Float16* p) {
    return *(const half8*)p;
}
static __device__ __forceinline__ int imin(int a, int b) { return a < b ? a : b; }

// wait until min(p[base..base+3]) >= need (wave-uniform), then acquire
static __device__ __forceinline__ void wait_ge(volatile int* p, int base, int need) {
    if (need <= 0) return;
    int guard = 0;
    for (;;) {
        const int m0 = p[base + 0], m1 = p[base + 1];
        const int m2 = p[base + 2], m3 = p[base + 3];
        if (imin(imin(m0, m1), imin(m2, m3)) >= need) break;
        __builtin_amdgcn_s_sleep(1);
        if (++guard > (1 << 22)) break;   // safety valve (never hit if correct)
    }
    __builtin_amdgcn_fence(__ATOMIC_ACQUIRE, "workgroup");
}
// release-publish: all prior LDS writes visible before flag store
static __device__ __forceinline__ void publish(volatile int* p, int idx, int val, int lane) {
    __builtin_amdgcn_fence(__ATOMIC_RELEASE, "workgroup");
    if (lane == 0) p[idx] = val;
}

__global__ __launch_bounds__(512, 1)
void gru_mfma(const float* __restrict__ x,
              const float* __restrict__ w_ih0, const float* __restrict__ w_hh0,
              const float* __restrict__ b_ih0, const float* __restrict__ b_hh0,
              const float* __restrict__ w_ih1, const float* __restrict__ w_hh1,
              const float* __restrict__ b_ih1, const float* __restrict__ b_hh1,
              const float* __restrict__ fc_w,  const float* __restrict__ fc_b,
              float* __restrict__ out)
{
    __shared__ __align__(16) float xs[T_LEN * 16];            // [t][m], 32 KB
    __shared__ __align__(16) _Float16 h0f[NSLOT][16 * KS];    // h0 ring
    __shared__ __align__(16) _Float16 h1f[NSLOT][16 * KS];    // h1 ring
    __shared__ int prog[8];                                   // per-wave progress
    __shared__ float red[64];

    const int tid  = threadIdx.x;
    const int wv   = tid >> 6;
    const int grp  = wv >> 2;       // 0 = layer-0 group, 1 = layer-1 group
    const int w    = wv & 3;        // N-split within group
    const int lane = tid & 63;
    const int n    = lane & 15;
    const int q    = lane >> 4;
    const int u    = w * 16 + n;    // unit owned in gate phase

    volatile int* vprog = prog;

    // ---- stage this block's 16 x-rows into LDS as [t][m] (coalesced) ----
    const float* xg = x + (size_t)(blockIdx.x * 16) * T_LEN;
    for (int i = tid; i < 16 * T_LEN; i += 512) {
        const int row = i >> 9, t = i & 511;
        xs[t * 16 + row] = xg[row * T_LEN + t];
    }
    // zero slot 3 of both rings (h(-1) = 0); zero all slots for safety
    for (int i = tid; i < NSLOT * 16 * KS; i += 512) {
        ((_Float16*)h0f)[i] = (_Float16)0;
        ((_Float16*)h1f)[i] = (_Float16)0;
    }
    if (tid < 8) prog[tid] = 0;

    // ---- loop-invariant weight B-fragments (single fp16), group-specific ----
    half8 B[3][4];
    {
        const int rows[3] = {u, 64 + u, 128 + u};
        const float* bc[4];
        if (grp == 0) {
            bc[0] = w_hh0;      bc[1] = w_hh0 + 32;
            bc[2] = w_hh0;      bc[3] = w_hh0 + 32;   // unused dups
        } else {
            bc[0] = w_ih1;      bc[1] = w_ih1 + 32;
            bc[2] = w_hh1;      bc[3] = w_hh1 + 32;
        }
        #pragma unroll
        for (int g = 0; g < 3; g++)
            #pragma unroll
            for (int c = 0; c < 4; c++) {
                const float* r0 = bc[c] + rows[g] * 64 + 8 * q;
                #pragma unroll
                for (int j = 0; j < 8; j++) B[g][c][j] = (_Float16)r0[j];
            }
    }

    // per-lane gate constants for unit u (group-specific)
    float wir = 0.f, wiz = 0.f, win = 0.f, brc = 0.f, bzc = 0.f, binc = 0.f, bhnc = 0.f;
    if (grp == 0) {
        wir = w_ih0[u]; wiz = w_ih0[64 + u]; win = w_ih0[128 + u];
        brc = b_ih0[u] + b_hh0[u];
        bzc = b_ih0[64 + u] + b_hh0[64 + u];
        binc = b_ih0[128 + u]; bhnc = b_hh0[128 + u];
    } else {
        brc = b_ih1[u] + b_hh1[u];
        bzc = b_ih1[64 + u] + b_hh1[64 + u];
        binc = b_ih1[128 + u]; bhnc = b_hh1[128 + u];
    }

    float hst[4] = {0.f, 0.f, 0.f, 0.f};   // fp32 h[m=4q+reg][u] (own layer)

    __syncthreads();   // staging + zeroed rings + prog visible to all

    const int abase = n * KS + 8 * q;       // A-frag base (fp16 elems)

    if (grp == 0) {
        // ================= layer-0 producer waves =================
        #pragma unroll 1
        for (int t = 0; t < T_LEN; t++) {
            wait_ge(vprog, 0, t);           // peers' h0(t-1)
            wait_ge(vprog, 4, t - 3);       // L1 done with h0(t-4) (ring slot)

            const int sr = (t - 1) & (NSLOT - 1);
            const int sw = t & (NSLOT - 1);
            const half8 a0 = ld8(&h0f[sr][abase]);
            const half8 a1 = ld8(&h0f[sr][abase + 32]);
            const v4f xv = *(const v4f*)(xs + t * 16 + 4 * q);

            v4f accR, accZ, accN;
            #pragma unroll
            for (int r = 0; r < 4; r++) {
                accR[r] = fmaf(xv[r], wir, brc);
                accZ[r] = fmaf(xv[r], wiz, bzc);
                accN[r] = 0.f;
            }
            accR = mfma16(a0, B[0][0], accR);
            accZ = mfma16(a0, B[1][0], accZ);
            accN = mfma16(a0, B[2][0], accN);
            accR = mfma16(a1, B[0][1], accR);
            accZ = mfma16(a1, B[1][1], accZ);
            accN = mfma16(a1, B[2][1], accN);

            #pragma unroll
            for (int r = 0; r < 4; r++) {
                const float rg = sigm(accR[r]);
                const float zg = sigm(accZ[r]);
                const float inn = fmaf(xv[r], win, binc);
                const float ng = tanh_fast(inn + rg * (accN[r] + bhnc));
                const float h = ng + zg * (hst[r] - ng);
                hst[r] = h;
                h0f[sw][(4 * q + r) * KS + u] = (_Float16)h;
            }
            publish(vprog, wv, t + 1, lane);
        }
    } else {
        // ================= layer-1 consumer waves =================
        #pragma unroll 1
        for (int s = 0; s < T_LEN; s++) {
            wait_ge(vprog, 0, s + 1);       // h0(s) available
            wait_ge(vprog, 4, s);           // peers' h1(s-1)

            const int s0 = s & (NSLOT - 1);         // h0(s) slot
            const int s1 = (s - 1) & (NSLOT - 1);   // h1(s-1) slot
            const half8 g00 = ld8(&h0f[s0][abase]);
            const half8 g01 = ld8(&h0f[s0][abase + 32]);
            const half8 g10 = ld8(&h1f[s1][abase]);
            const half8 g11 = ld8(&h1f[s1][abase + 32]);

            v4f aR, aZ, aNi, aNh;
            #pragma unroll
            for (int r = 0; r < 4; r++) {
                aR[r] = brc;  aZ[r] = bzc;  aNi[r] = binc;  aNh[r] = bhnc;
            }
            aR  = mfma16(g00, B[0][0], aR);
            aZ  = mfma16(g00, B[1][0], aZ);
            aNi = mfma16(g00, B[2][0], aNi);
            aNh = mfma16(g10, B[2][2], aNh);
            aR  = mfma16(g01, B[0][1], aR);
            aZ  = mfma16(g01, B[1][1], aZ);
            aNi = mfma16(g01, B[2][1], aNi);
            aNh = mfma16(g11, B[2][3], aNh);
            aR  = mfma16(g10, B[0][2], aR);
            aZ  = mfma16(g10, B[1][2], aZ);
            aR  = mfma16(g11, B[0][3], aR);
            aZ  = mfma16(g11, B[1][3], aZ);

            #pragma unroll
            for (int r = 0; r < 4; r++) {
                const float rg = sigm(aR[r]);
                const float zg = sigm(aZ[r]);
                const float ng = tanh_fast(aNi[r] + rg * aNh[r]);
                const float h = ng + zg * (hst[r] - ng);
                hst[r] = h;
                h1f[s0][(4 * q + r) * KS + u] = (_Float16)h;
            }
            publish(vprog, wv, s + 1, lane);
        }
    }

    __syncthreads();   // converge before FC epilogue

    // ======== FC epilogue: out[m] = sum_u fc_w[u] h1[m][u] + fc_b ========
    if (grp == 1) {
        const float fw = fc_w[u];
        #pragma unroll
        for (int r = 0; r < 4; r++) {
            float v = fw * hst[r];
            v += __shfl_xor(v, 1, 64);
            v += __shfl_xor(v, 2, 64);
            v += __shfl_xor(v, 4, 64);
            v += __shfl_xor(v, 8, 64);   // sum over 16 n-lanes (q preserved)
            if (n == 0) red[(4 * q + r) * 4 + w] = v;
        }
    }
    __syncthreads();
    if (tid < 16) {
        const float s = red[tid * 4] + red[tid * 4 + 1] + red[tid * 4 + 2] + red[tid * 4 + 3];
        out[blockIdx.x * 16 + tid] = s + fc_b[0];
    }
}

extern "C" void kernel_launch(void* const* d_in, const int* in_sizes, int n_in,
                              void* d_out, int out_size, void* d_ws, size_t ws_size,
                              hipStream_t stream)
{
    const float* x     = (const float*)d_in[0];
    const float* w_ih0 = (const float*)d_in[1];
    const float* w_hh0 = (const float*)d_in[2];
    const float* b_ih0 = (const float*)d_in[3];
    const float* b_hh0 = (const float*)d_in[4];
    const float* w_ih1 = (const float*)d_in[5];
    const float* w_hh1 = (const float*)d_in[6];
    const float* b_ih1 = (const float*)d_in[7];
    const float* b_hh1 = (const float*)d_in[8];
    const float* fc_w  = (const float*)d_in[9];
    const float* fc_b  = (const float*)d_in[10];
    float* out = (float*)d_out;

    hipLaunchKernelGGL(gru_mfma, dim3(256), dim3(512), 0, stream,
                       x, w_ih0, w_hh0, b_ih0, b_hh0,
                       w_ih1, w_hh1, b_ih1, b_hh1, fc_w, fc_b, out);
}